// Round 6
// baseline (210.871 us; speedup 1.0000x reference)
//
#include <hip/hip_runtime.h>
#include <math.h>

#define T_TOK 4096
#define A_DIM 1024
#define E_DIM 512
#define N_SPAN 32768
#define W_MAX 10
#define HID 150
#define FD 20

#define PR  160             // P row stride (bf16 elems); cols 150..159 zero
#define KP2 160             // padded K/N for the 150x150 layers

// ---- workspace layout (float offsets) ----
#define WS_ATTNS 0
#define WS_PB    4096                    // 3 x 4096 x 160 ushort = 983,040 floats
#define WS_WPACK (4096 + 983040)
// Pb ushort offsets
#define PB_P1 0
#define PB_P2 655360
#define PB_P3 1310720
// wpack ushort offsets
#define WP_A1  0
#define WP_S1A 163840
#define WP_S1B 327680
#define WP_V   491520
#define WP_A2  573440
#define WP_S2  599040
#define WP_WE1 624640
#define WP_TOTAL 626080

typedef short  bf16x8 __attribute__((ext_vector_type(8)));
typedef float  f32x4  __attribute__((ext_vector_type(4)));

__device__ __forceinline__ float4 ld4(const float* p) { return *(const float4*)p; }

__device__ __forceinline__ unsigned short f2bf(float f) {
    unsigned u = __float_as_uint(f);
    unsigned r = u + 0x7fffu + ((u >> 16) & 1u);   // RNE
    return (unsigned short)(r >> 16);
}
__device__ __forceinline__ float bf2f(short s) {
    return __uint_as_float(((unsigned)(unsigned short)s) << 16);
}

// build an A-frag (8 consecutive k) from fp32 memory
__device__ __forceinline__ bf16x8 cvt_frag(const float* p) {
    float4 u = ld4(p), v = ld4(p + 4);
    bf16x8 f;
    f[0] = (short)f2bf(u.x); f[1] = (short)f2bf(u.y);
    f[2] = (short)f2bf(u.z); f[3] = (short)f2bf(u.w);
    f[4] = (short)f2bf(v.x); f[5] = (short)f2bf(v.y);
    f[6] = (short)f2bf(v.z); f[7] = (short)f2bf(v.w);
    return f;
}

// ---------------------------------------------------------------------------
// Prepack: weights -> bf16 n-major [n][k] + WE1 = width_emb @ Ws1[2560:] (bf16).
// ---------------------------------------------------------------------------
__global__ __launch_bounds__(256) void prepack_kernel(
    const float* __restrict__ Wa1, const float* __restrict__ Ws1,
    const float* __restrict__ Wa2, const float* __restrict__ Ws2,
    const float* __restrict__ width_emb, unsigned short* __restrict__ wp)
{
    int idx = blockIdx.x * 256 + threadIdx.x;
    if (idx >= WP_TOTAL) return;
    if (idx < WP_WE1) {
        int kk = idx / KP2, n = idx % KP2;
        float v = 0.f;
        int dst;
        if (kk < 3072) {                          // Wa1 / Ws1a / Ws1b, K=1024
            int which = kk >> 10, k = kk & 1023;
            if (n < HID) {
                if (which == 0)      v = Wa1[(size_t)k * HID + n];
                else if (which == 1) v = Ws1[(size_t)k * HID + n];
                else                 v = Ws1[(size_t)(1024 + k) * HID + n];
            }
            dst = which * 163840 + n * 1024 + k;
        } else if (kk < 3584) {                   // V block, K=512
            int k = kk - 3072;
            if (n < HID) v = Ws1[(size_t)(2048 + k) * HID + n];
            dst = WP_V + n * 512 + k;
        } else if (kk < 3744) {                   // Wa2
            int k = kk - 3584;
            if (n < HID && k < HID) v = Wa2[(size_t)k * HID + n];
            dst = WP_A2 + n * KP2 + k;
        } else {                                  // Ws2
            int k = kk - 3744;
            if (n < HID && k < HID) v = Ws2[(size_t)k * HID + n];
            dst = WP_S2 + n * KP2 + k;
        }
        wp[dst] = f2bf(v);
    } else {                                      // WE1[9][160] bf16
        int e = idx - WP_WE1;
        int b = e / KP2, n = e % KP2;
        float acc = 0.f;
        if (n < HID) {
            for (int k = 0; k < FD; ++k)
                acc = fmaf(width_emb[b * FD + k], Ws1[(size_t)(2560 + k) * HID + n], acc);
        }
        wp[idx] = f2bf(acc);
    }
}

// ---------------------------------------------------------------------------
// Token kernel v2: 448 blocks x 4 waves = 1792 independent wave-tasks.
//   task <  256 : g0-full — 16 rows x 10 Wa1 tiles (K=1024) + fused attn-MLP
//                 tail in-wave (per-wave LDS patch, no barriers) -> attns.
//   task < 1280 : states x {Ws1a,Ws1b} in 5-tile groups -> P1/P2 (bf16).
//   task < 1792 : embeds x V in 5-tile groups (K=512)   -> P3 (bf16).
// 5-tile groups keep acc=20 VGPR so all 5 B-loads + next A stay in flight.
// ---------------------------------------------------------------------------
__global__ __launch_bounds__(256, 4) void token_kernel(
    const float* __restrict__ states, const float* __restrict__ embeds,
    const unsigned short* __restrict__ wp,
    const float* __restrict__ ba1, const float* __restrict__ ba2,
    const float* __restrict__ Wa3, const float* __restrict__ ba3,
    unsigned short* __restrict__ Pb, float* __restrict__ attns)
{
    __shared__ unsigned short h1[4][16][168];   // per-wave transpose patch
    const int tid = threadIdx.x;
    const int wv = tid >> 6, lane = tid & 63, l15 = lane & 15, quad = lane >> 4;
    const int task = blockIdx.x * 4 + wv;

    if (task < 256) {
        // ---- g0: 16 rows x 160 cols of Wa1, K=1024, + fused attn tail ----
        const int m0 = task * 16;
        f32x4 acc[10];
#pragma unroll
        for (int t = 0; t < 10; ++t)
#pragma unroll
            for (int i = 0; i < 4; ++i) acc[t][i] = 0.f;

        const float* a0 = states + (size_t)(m0 + l15) * A_DIM + quad * 8;
        const unsigned short* b0 = wp + (size_t)l15 * 1024 + quad * 8;

        for (int k0 = 0; k0 < A_DIM; k0 += 32) {
            bf16x8 af = cvt_frag(a0 + k0);
#pragma unroll
            for (int t = 0; t < 10; ++t) {
                bf16x8 b = *(const bf16x8*)(b0 + t * 16384 + k0);
                acc[t] = __builtin_amdgcn_mfma_f32_16x16x32_bf16(af, b, acc[t], 0, 0, 0);
            }
        }
        // C-layout -> per-wave LDS patch (bf16), biased + relu
#pragma unroll
        for (int t = 0; t < 10; ++t) {
            int col = t * 16 + l15;
            float b = (col < HID) ? ba1[col] : 0.f;
#pragma unroll
            for (int i = 0; i < 4; ++i)
                h1[wv][quad * 4 + i][col] = f2bf(fmaxf(acc[t][i] + b, 0.f));
        }
        // zero k-pad cols 160..167 not needed (loop reads only k<160)
        // layer2: h1 @ Wa2 (K=160), all 10 n-tiles in this wave
        f32x4 a2[10];
#pragma unroll
        for (int t = 0; t < 10; ++t)
#pragma unroll
            for (int i = 0; i < 4; ++i) a2[t][i] = 0.f;
#pragma unroll
        for (int c = 0; c < 5; ++c) {
            int k0 = c * 32;
            bf16x8 af = *(const bf16x8*)&h1[wv][l15][k0 + quad * 8];
#pragma unroll
            for (int t = 0; t < 10; ++t) {
                bf16x8 b = *(const bf16x8*)(wp + WP_A2 +
                            (size_t)(t * 16 + l15) * KP2 + k0 + quad * 8);
                a2[t] = __builtin_amdgcn_mfma_f32_16x16x32_bf16(af, b, a2[t], 0, 0, 0);
            }
        }
        // layer3: relu(a2 + ba2) . Wa3 -> shuffle-reduce over l15
        float sc[4] = {0.f, 0.f, 0.f, 0.f};
#pragma unroll
        for (int t = 0; t < 10; ++t) {
            int col = t * 16 + l15;
            float w3 = (col < HID) ? Wa3[col] : 0.f;
            float b2 = (col < HID) ? ba2[col] : 0.f;
#pragma unroll
            for (int i = 0; i < 4; ++i)
                sc[i] = fmaf(fmaxf(a2[t][i] + b2, 0.f), w3, sc[i]);
        }
#pragma unroll
        for (int off = 8; off >= 1; off >>= 1)
#pragma unroll
            for (int i = 0; i < 4; ++i) sc[i] += __shfl_down(sc[i], off, 16);
        if (l15 == 0) {
            float b3 = ba3[0];
#pragma unroll
            for (int i = 0; i < 4; ++i) attns[m0 + quad * 4 + i] = sc[i] + b3;
        }
    } else if (task < 1280) {
        // ---- states x Ws1a/Ws1b, 5-tile group ----
        const int e = task - 256;
        const int m0 = (e >> 2) * 16;
        const int sub = e & 3, g = 1 + (sub >> 1), grp5 = sub & 1;

        f32x4 acc[5];
#pragma unroll
        for (int t = 0; t < 5; ++t)
#pragma unroll
            for (int i = 0; i < 4; ++i) acc[t][i] = 0.f;

        const float* a0 = states + (size_t)(m0 + l15) * A_DIM + quad * 8;
        const unsigned short* b0 = wp + (size_t)g * 163840 +
                                   (size_t)(grp5 * 80 + l15) * 1024 + quad * 8;

        for (int k0 = 0; k0 < A_DIM; k0 += 32) {
            bf16x8 af = cvt_frag(a0 + k0);
#pragma unroll
            for (int t = 0; t < 5; ++t) {
                bf16x8 b = *(const bf16x8*)(b0 + t * 16384 + k0);
                acc[t] = __builtin_amdgcn_mfma_f32_16x16x32_bf16(af, b, acc[t], 0, 0, 0);
            }
        }
        unsigned short* Pg = Pb + (size_t)(g - 1) * 655360;
#pragma unroll
        for (int t = 0; t < 5; ++t) {
            int col = grp5 * 80 + t * 16 + l15;
#pragma unroll
            for (int i = 0; i < 4; ++i)
                Pg[(size_t)(m0 + quad * 4 + i) * PR + col] =
                    (col < HID) ? f2bf(acc[t][i]) : (unsigned short)0;
        }
    } else {
        // ---- embeds x V, 5-tile group, K=512 ----
        const int e = task - 1280;
        const int m0 = (e >> 1) * 16;
        const int grp5 = e & 1;

        f32x4 acc[5];
#pragma unroll
        for (int t = 0; t < 5; ++t)
#pragma unroll
            for (int i = 0; i < 4; ++i) acc[t][i] = 0.f;

        const float* a0 = embeds + (size_t)(m0 + l15) * E_DIM + quad * 8;
        const unsigned short* b0 = wp + WP_V +
                                   (size_t)(grp5 * 80 + l15) * 512 + quad * 8;

        for (int k0 = 0; k0 < E_DIM; k0 += 32) {
            bf16x8 af = cvt_frag(a0 + k0);
#pragma unroll
            for (int t = 0; t < 5; ++t) {
                bf16x8 b = *(const bf16x8*)(b0 + t * 8192 + k0);
                acc[t] = __builtin_amdgcn_mfma_f32_16x16x32_bf16(af, b, acc[t], 0, 0, 0);
            }
        }
        unsigned short* P3 = Pb + PB_P3;
#pragma unroll
        for (int t = 0; t < 5; ++t) {
            int col = grp5 * 80 + t * 16 + l15;
#pragma unroll
            for (int i = 0; i < 4; ++i)
                P3[(size_t)(m0 + quad * 4 + i) * PR + col] =
                    (col < HID) ? f2bf(acc[t][i]) : (unsigned short)0;
        }
    }
}

// ---------------------------------------------------------------------------
// Span kernel: 32 spans/block, grid 1024. Gather-combine from bf16 P
// (XCD-L2 resident) -> h1 bf16 in LDS; layer2 MFMA; layer3 shuffle-reduce.
// ---------------------------------------------------------------------------
__global__ __launch_bounds__(256) void span_kernel(
    const unsigned short* __restrict__ Pb, const float* __restrict__ attns,
    const unsigned short* __restrict__ wp,
    const int* __restrict__ span_starts, const int* __restrict__ span_widths,
    const float* __restrict__ bs1, const float* __restrict__ bs2,
    const float* __restrict__ Ws3, const float* __restrict__ bs3,
    float* __restrict__ out)
{
    __shared__ unsigned short sHb[32][168];
    __shared__ float s_wgt[32][W_MAX];
    __shared__ int s_st[32], s_wd[32], s_bin[32];
    __shared__ float sPart[4][32];
    __shared__ float sb1[KP2];

    const int tid = threadIdx.x;
    const int n0s = blockIdx.x * 32;

    if (tid < KP2) sb1[tid] = (tid < HID) ? bs1[tid] : 0.f;
    if (tid < 32) {
        int st = span_starts[n0s + tid], wd = span_widths[n0s + tid];
        s_st[tid] = st; s_wd[tid] = wd;
        s_bin[tid] = (wd >= 1) + (wd >= 2) + (wd >= 3) + (wd >= 4) +
                     (wd >= 8) + (wd >= 16) + (wd >= 32) + (wd >= 64);
        float lg[W_MAX];
        float m = -1e30f;
#pragma unroll
        for (int w = 0; w < W_MAX; ++w)
            if (w < wd) { float a = attns[st + w]; lg[w] = a; m = fmaxf(m, a); }
        float sum = 0.f;
#pragma unroll
        for (int w = 0; w < W_MAX; ++w) {
            float e = (w < wd) ? __expf(lg[w] - m) : 0.f;
            lg[w] = e; sum += e;
        }
        float inv = 1.f / sum;
#pragma unroll
        for (int w = 0; w < W_MAX; ++w) s_wgt[tid][w] = lg[w] * inv;
    }
    __syncthreads();

    // gather-combine: 8 lanes/span, bf16x8 chunks
    {
        const unsigned short* P1b = Pb + PB_P1;
        const unsigned short* P2b = Pb + PB_P2;
        const unsigned short* P3b = Pb + PB_P3;
        const unsigned short* WEb = wp + WP_WE1;
        const int s = tid >> 3, jl = tid & 7;
        const int st = s_st[s], wd = s_wd[s];
        const size_t rs = (size_t)st * PR;
        const size_t re = (size_t)(st + wd - 1) * PR;
        const size_t rb = (size_t)s_bin[s] * PR;
        for (int c = jl; c < 20; c += 8) {
            const int j = c * 8;
            bf16x8 u1 = *(const bf16x8*)(P1b + rs + j);
            bf16x8 u2 = *(const bf16x8*)(P2b + re + j);
            bf16x8 uw = *(const bf16x8*)(WEb + rb + j);
            float acc[8];
#pragma unroll
            for (int i = 0; i < 8; ++i)
                acc[i] = bf2f(u1[i]) + bf2f(u2[i]) + bf2f(uw[i]) + sb1[j + i];
#pragma unroll
            for (int w = 0; w < W_MAX; ++w) {
                if (w < wd) {
                    float wt = s_wgt[s][w];
                    bf16x8 uv = *(const bf16x8*)(P3b + rs + (size_t)w * PR + j);
#pragma unroll
                    for (int i = 0; i < 8; ++i)
                        acc[i] = fmaf(wt, bf2f(uv[i]), acc[i]);
                }
            }
            bf16x8 pk;
#pragma unroll
            for (int i = 0; i < 8; ++i) pk[i] = (short)f2bf(fmaxf(acc[i], 0.f));
            *(bf16x8*)&sHb[s][j] = pk;
        }
    }
    __syncthreads();

    // layer2 MFMA: M=32 (2 m-tiles), N=160 (tiles 3,3,2,2 over waves)
    const int wv = tid >> 6, lane = tid & 63, l15 = lane & 15, quad = lane >> 4;
    const int nb = (wv < 2) ? wv * 3 : 6 + (wv - 2) * 2;
    const int cnt = (wv < 2) ? 3 : 2;

    f32x4 a2[2][3];
#pragma unroll
    for (int mt = 0; mt < 2; ++mt)
#pragma unroll
        for (int t = 0; t < 3; ++t)
#pragma unroll
            for (int i = 0; i < 4; ++i) a2[mt][t][i] = 0.f;

#pragma unroll
    for (int c = 0; c < 5; ++c) {
        int k0 = c * 32;
        bf16x8 af0 = *(const bf16x8*)&sHb[l15][k0 + quad * 8];
        bf16x8 af1 = *(const bf16x8*)&sHb[16 + l15][k0 + quad * 8];
#pragma unroll
        for (int t = 0; t < 3; ++t) {
            if (t < cnt) {
                bf16x8 b = *(const bf16x8*)(wp + WP_S2 +
                            (size_t)((nb + t) * 16 + l15) * KP2 + k0 + quad * 8);
                a2[0][t] = __builtin_amdgcn_mfma_f32_16x16x32_bf16(af0, b, a2[0][t], 0, 0, 0);
                a2[1][t] = __builtin_amdgcn_mfma_f32_16x16x32_bf16(af1, b, a2[1][t], 0, 0, 0);
            }
        }
    }

    float sc[2][4];
#pragma unroll
    for (int mt = 0; mt < 2; ++mt)
#pragma unroll
        for (int i = 0; i < 4; ++i) sc[mt][i] = 0.f;
#pragma unroll
    for (int t = 0; t < 3; ++t) {
        if (t < cnt) {
            int col = (nb + t) * 16 + l15;
            float w3 = (col < HID) ? Ws3[col] : 0.f;
            float b2 = (col < HID) ? bs2[col] : 0.f;
#pragma unroll
            for (int mt = 0; mt < 2; ++mt)
#pragma unroll
                for (int i = 0; i < 4; ++i)
                    sc[mt][i] = fmaf(fmaxf(a2[mt][t][i] + b2, 0.f), w3, sc[mt][i]);
        }
    }
#pragma unroll
    for (int off = 8; off >= 1; off >>= 1)
#pragma unroll
        for (int mt = 0; mt < 2; ++mt)
#pragma unroll
            for (int i = 0; i < 4; ++i)
                sc[mt][i] += __shfl_down(sc[mt][i], off, 16);
    if (l15 == 0) {
#pragma unroll
        for (int mt = 0; mt < 2; ++mt)
#pragma unroll
            for (int i = 0; i < 4; ++i)
                sPart[wv][mt * 16 + quad * 4 + i] = sc[mt][i];
    }
    __syncthreads();
    if (tid < 32)
        out[n0s + tid] = sPart[0][tid] + sPart[1][tid] + sPart[2][tid] +
                         sPart[3][tid] + bs3[0];
}

// ---------------------------------------------------------------------------
extern "C" void kernel_launch(void* const* d_in, const int* in_sizes, int n_in,
                              void* d_out, int out_size, void* d_ws, size_t ws_size,
                              hipStream_t stream)
{
    const float* states      = (const float*)d_in[0];
    const float* embeds      = (const float*)d_in[1];
    const int*   span_starts = (const int*)d_in[2];
    const int*   span_widths = (const int*)d_in[3];
    const float* Wa1 = (const float*)d_in[4];
    const float* ba1 = (const float*)d_in[5];
    const float* Wa2 = (const float*)d_in[6];
    const float* ba2 = (const float*)d_in[7];
    const float* Wa3 = (const float*)d_in[8];
    const float* ba3 = (const float*)d_in[9];
    const float* width_emb = (const float*)d_in[10];
    const float* Ws1 = (const float*)d_in[11];
    const float* bs1 = (const float*)d_in[12];
    const float* Ws2 = (const float*)d_in[13];
    const float* bs2 = (const float*)d_in[14];
    const float* Ws3 = (const float*)d_in[15];
    const float* bs3 = (const float*)d_in[16];
    float* out = (float*)d_out;

    float* ws    = (float*)d_ws;
    float* attns = ws + WS_ATTNS;
    unsigned short* Pb    = (unsigned short*)(ws + WS_PB);
    unsigned short* wpack = (unsigned short*)(ws + WS_WPACK);

    hipLaunchKernelGGL(prepack_kernel, dim3((WP_TOTAL + 255) / 256), dim3(256), 0, stream,
                       Wa1, Ws1, Wa2, Ws2, width_emb, wpack);
    hipLaunchKernelGGL(token_kernel, dim3(448), dim3(256), 0, stream,
                       states, embeds, wpack, ba1, ba2, Wa3, ba3, Pb, attns);
    hipLaunchKernelGGL(span_kernel, dim3(N_SPAN / 32), dim3(256), 0, stream,
                       Pb, attns, wpack, span_starts, span_widths,
                       bs1, bs2, Ws3, bs3, out);
}

// Round 7
// 173.782 us; speedup vs baseline: 1.2134x; 1.2134x over previous
//
#include <hip/hip_runtime.h>
#include <math.h>

#define T_TOK 4096
#define A_DIM 1024
#define E_DIM 512
#define N_SPAN 32768
#define W_MAX 10
#define HID 150
#define FD 20

#define PR  160             // P row stride (bf16 elems); cols 150..159 zero
#define KP2 160             // padded K/N for the 150x150 layers

// ---- workspace layout (float offsets) ----
#define WS_ATTNS 0
#define WS_PB    4096                    // 3 x 4096 x 160 ushort = 983,040 floats
#define WS_WPACK (4096 + 983040)         // = 987,136
// Pb ushort offsets
#define PB_P1 0
#define PB_P2 655360
#define PB_P3 1310720
// wpack ushort offsets (all regions quad-aligned, enumerated linearly)
#define WP_ST  0            // [512][1024]: n 0-159 Wa1, 160-319 Ws1a, 320-479 Ws1b, 480-511 zero
#define WP_V   524288       // [192][512]: n 0-159 V, 160-191 zero
#define WP_A2  622592       // [160][160]
#define WP_S2  648192       // [160][160]
#define WP_WE1 673792       // [9][160]
#define WP_TOTAL 675232
#define PK_QUADS 168808     // WP_TOTAL/4

typedef short  bf16x8 __attribute__((ext_vector_type(8)));
typedef float  f32x4  __attribute__((ext_vector_type(4)));

__device__ __forceinline__ float4 ld4(const float* p) { return *(const float4*)p; }

__device__ __forceinline__ unsigned short f2bf(float f) {
    unsigned u = __float_as_uint(f);
    unsigned r = u + 0x7fffu + ((u >> 16) & 1u);   // RNE
    return (unsigned short)(r >> 16);
}
__device__ __forceinline__ float bf2f(short s) {
    return __uint_as_float(((unsigned)(unsigned short)s) << 16);
}

// async global->LDS, 16 B per lane; LDS dst is wave-uniform base + lane*16
typedef const __attribute__((address_space(1))) unsigned int as1_u32;
typedef __attribute__((address_space(3))) unsigned int as3_u32;
__device__ __forceinline__ void dma16(const void* g, void* l) {
    __builtin_amdgcn_global_load_lds((as1_u32*)g, (as3_u32*)l, 16, 0, 0);
}
template<int N> __device__ __forceinline__ void waitv() {
    asm volatile("s_waitcnt vmcnt(%0)" :: "n"(N) : "memory");
}
#define CFENCE asm volatile("" ::: "memory")

__device__ __forceinline__ bf16x8 cvt_regs(const float4* a) {
    bf16x8 f;
    f[0] = (short)f2bf(a[0].x); f[1] = (short)f2bf(a[0].y);
    f[2] = (short)f2bf(a[0].z); f[3] = (short)f2bf(a[0].w);
    f[4] = (short)f2bf(a[1].x); f[5] = (short)f2bf(a[1].y);
    f[6] = (short)f2bf(a[1].z); f[7] = (short)f2bf(a[1].w);
    return f;
}

// ---------------------------------------------------------------------------
// Prepack: weights -> bf16 n-major [n][k] with zeroed pads + WE1. Each thread
// produces 4 consecutive k (one ushort4, fully write-coalesced); dst = t4*4.
// ---------------------------------------------------------------------------
__global__ __launch_bounds__(256) void prepack_kernel(
    const float* __restrict__ Wa1, const float* __restrict__ Ws1,
    const float* __restrict__ Wa2, const float* __restrict__ Ws2,
    const float* __restrict__ width_emb, unsigned short* __restrict__ wp)
{
    int t4 = blockIdx.x * 256 + threadIdx.x;
    if (t4 >= PK_QUADS) return;
    unsigned short r0 = 0, r1 = 0, r2 = 0, r3 = 0;
    if (t4 < 131072) {                        // states pack [512][1024]
        int n = t4 >> 8, k = (t4 & 255) * 4;
        if (n < 480) {
            int which = n / 160, nn = n - which * 160;
            if (nn < HID) {
                const float* W = (which == 0) ? Wa1 : Ws1 + (size_t)(which - 1) * 1024 * HID;
                r0 = f2bf(W[(size_t)(k + 0) * HID + nn]);
                r1 = f2bf(W[(size_t)(k + 1) * HID + nn]);
                r2 = f2bf(W[(size_t)(k + 2) * HID + nn]);
                r3 = f2bf(W[(size_t)(k + 3) * HID + nn]);
            }
        }
    } else if (t4 < 155648) {                 // V [192][512]
        int e = t4 - 131072, n = e >> 7, k = (e & 127) * 4;
        if (n < HID) {
            r0 = f2bf(Ws1[(size_t)(2048 + k + 0) * HID + n]);
            r1 = f2bf(Ws1[(size_t)(2048 + k + 1) * HID + n]);
            r2 = f2bf(Ws1[(size_t)(2048 + k + 2) * HID + n]);
            r3 = f2bf(Ws1[(size_t)(2048 + k + 3) * HID + n]);
        }
    } else if (t4 < 162048) {                 // Wa2 [160][160]
        int e = t4 - 155648, n = e / 40, k = (e - n * 40) * 4;
        if (n < HID) {
            if (k + 0 < HID) r0 = f2bf(Wa2[(k + 0) * HID + n]);
            if (k + 1 < HID) r1 = f2bf(Wa2[(k + 1) * HID + n]);
            if (k + 2 < HID) r2 = f2bf(Wa2[(k + 2) * HID + n]);
            if (k + 3 < HID) r3 = f2bf(Wa2[(k + 3) * HID + n]);
        }
    } else if (t4 < 168448) {                 // Ws2 [160][160]
        int e = t4 - 162048, n = e / 40, k = (e - n * 40) * 4;
        if (n < HID) {
            if (k + 0 < HID) r0 = f2bf(Ws2[(k + 0) * HID + n]);
            if (k + 1 < HID) r1 = f2bf(Ws2[(k + 1) * HID + n]);
            if (k + 2 < HID) r2 = f2bf(Ws2[(k + 2) * HID + n]);
            if (k + 3 < HID) r3 = f2bf(Ws2[(k + 3) * HID + n]);
        }
    } else {                                  // WE1 [9][160]
        int e = t4 - 168448, b = e / 40, n0 = (e - b * 40) * 4;
        unsigned short* rr[4] = {&r0, &r1, &r2, &r3};
#pragma unroll
        for (int i = 0; i < 4; ++i) {
            int n = n0 + i;
            if (n < HID) {
                float a = 0.f;
                for (int kk = 0; kk < FD; ++kk)
                    a = fmaf(width_emb[b * FD + kk], Ws1[(size_t)(2560 + kk) * HID + n], a);
                *rr[i] = f2bf(a);
            }
        }
    }
    ushort4 pk = {r0, r1, r2, r3};
    *(ushort4*)(wp + (size_t)t4 * 4) = pk;
}

// ---------------------------------------------------------------------------
// Token kernel: 512 blocks x 256 threads, 64 KB LDS, 2 blocks/CU.
//  bid <  256: states-block M=16: 32 n-tiles (8/wave incl. 2 pad) K=1024,
//              per-wave DMA double-buffer, fused attn-MLP tail.
//  bid >= 256: embeds-block M=16: 12 n-tiles (3/wave) K=512 -> P3.
// Pipeline per iter: cvt A(c); waitv<tc+4>; 8x(ds_read+MFMA); DMA(c+2);
// loadA(c+3). No barriers in the K-loop.
// ---------------------------------------------------------------------------
__global__ __launch_bounds__(256, 2) void token_kernel(
    const float* __restrict__ states, const float* __restrict__ embeds,
    const unsigned short* __restrict__ wp,
    const float* __restrict__ ba1, const float* __restrict__ ba2,
    const float* __restrict__ Wa3, const float* __restrict__ ba3,
    unsigned short* __restrict__ Pb, float* __restrict__ attns)
{
    __shared__ unsigned short Bst[2][4][8][512];   // 64 KB exactly

    const int tid = threadIdx.x;
    const int wv = tid >> 6, lane = tid & 63, l15 = lane & 15, quad = lane >> 4;

    if (blockIdx.x < 256) {
        const int m0 = blockIdx.x * 16;
        const float* aPtr = states + (size_t)(m0 + l15) * A_DIM + quad * 8;
        const int tb = wv * 8;   // global tile base for this wave
        const unsigned short* dSrc = wp + WP_ST +
            ((size_t)tb * 16 + (lane >> 2)) * 1024 + (lane & 3) * 8;

        f32x4 acc[8];
#pragma unroll
        for (int t = 0; t < 8; ++t)
#pragma unroll
            for (int i = 0; i < 4; ++i) acc[t][i] = 0.f;
        float4 aReg[3][2];

#define ST_LOADA(slot, c) { aReg[slot][0] = ld4(aPtr + (c) * 32); \
                            aReg[slot][1] = ld4(aPtr + (c) * 32 + 4); }
#define ST_DMA(c) { _Pragma("unroll")                                      \
        for (int t = 0; t < 8; ++t)                                        \
            dma16(dSrc + (size_t)t * 16384 + (c) * 32,                     \
                  &Bst[(c) & 1][wv][t][0]); }
#define ST_BODY(c, WN, DOD, DOA) {                                         \
        bf16x8 af = cvt_regs(aReg[(c) % 3]);                               \
        waitv<WN>();                                                       \
        const unsigned short* Bw = &Bst[(c) & 1][wv][0][0];                \
        _Pragma("unroll")                                                  \
        for (int t = 0; t < 8; ++t) {                                      \
            bf16x8 bf = *(const bf16x8*)(Bw + t * 512 + l15 * 32 + quad * 8); \
            acc[t] = __builtin_amdgcn_mfma_f32_16x16x32_bf16(af, bf, acc[t], 0, 0, 0); \
        }                                                                  \
        CFENCE;                                                            \
        if (DOD) ST_DMA((c) + 2);                                          \
        CFENCE;                                                            \
        if (DOA) ST_LOADA((c) % 3, (c) + 3);                               \
        CFENCE; }

        // prime: A0; D0; A1; D1; A2
        ST_LOADA(0, 0); CFENCE;
        ST_DMA(0); CFENCE;
        ST_LOADA(1, 1); CFENCE;
        ST_DMA(1); CFENCE;
        ST_LOADA(2, 2); CFENCE;

        for (int c = 0; c <= 29; ++c) ST_BODY(c, 12, true, (c + 3) < 32);
        ST_BODY(30, 10, false, false);
        ST_BODY(31, 0, false, false);

        // epilogue: P1/P2 stores for tiles 10..29; tiles 0..9 -> h1a patch
        unsigned short (*h1a)[168] = (unsigned short (*)[168]) & Bst[0][0][0][0];
#pragma unroll
        for (int t = 0; t < 8; ++t) {
            const int tg = tb + t;
            const int col = tg * 16 + l15;
            if (tg >= 10 && tg < 30) {
                const int g = (tg < 20) ? 0 : 1;
                const int cc = col - 160 - g * 160;
                unsigned short* Pg = Pb + (size_t)g * 655360;
#pragma unroll
                for (int i = 0; i < 4; ++i)
                    Pg[(size_t)(m0 + quad * 4 + i) * PR + cc] =
                        (cc < HID) ? f2bf(acc[t][i]) : (unsigned short)0;
            }
        }
        __syncthreads();   // all DMAs drained per-wave; sync before h1a alias
#pragma unroll
        for (int t = 0; t < 8; ++t) {
            const int tg = tb + t;
            if (tg < 10) {
                const int col = tg * 16 + l15;
                const float b = (col < HID) ? ba1[col] : 0.f;
#pragma unroll
                for (int i = 0; i < 4; ++i)
                    h1a[quad * 4 + i][col] = f2bf(fmaxf(acc[t][i] + b, 0.f));
            }
        }
        __syncthreads();

        if (wv == 0) {   // fused attn tail: h1a @ Wa2 -> relu -> .Wa3
            f32x4 a2[10];
#pragma unroll
            for (int t = 0; t < 10; ++t)
#pragma unroll
                for (int i = 0; i < 4; ++i) a2[t][i] = 0.f;
#pragma unroll
            for (int cc = 0; cc < 5; ++cc) {
                const int k0 = cc * 32;
                bf16x8 af = *(const bf16x8*)&h1a[l15][k0 + quad * 8];
#pragma unroll
                for (int t = 0; t < 10; ++t) {
                    bf16x8 b = *(const bf16x8*)(wp + WP_A2 +
                                (size_t)(t * 16 + l15) * KP2 + k0 + quad * 8);
                    a2[t] = __builtin_amdgcn_mfma_f32_16x16x32_bf16(af, b, a2[t], 0, 0, 0);
                }
            }
            float sc[4] = {0.f, 0.f, 0.f, 0.f};
#pragma unroll
            for (int t = 0; t < 10; ++t) {
                const int col = t * 16 + l15;
                const float w3 = (col < HID) ? Wa3[col] : 0.f;
                const float b2 = (col < HID) ? ba2[col] : 0.f;
#pragma unroll
                for (int i = 0; i < 4; ++i)
                    sc[i] = fmaf(fmaxf(a2[t][i] + b2, 0.f), w3, sc[i]);
            }
#pragma unroll
            for (int off = 8; off >= 1; off >>= 1)
#pragma unroll
                for (int i = 0; i < 4; ++i) sc[i] += __shfl_down(sc[i], off, 16);
            if (l15 == 0) {
                const float b3 = ba3[0];
#pragma unroll
                for (int i = 0; i < 4; ++i) attns[m0 + quad * 4 + i] = sc[i] + b3;
            }
        }
    } else {
        // ---- embeds block: M=16, 12 tiles (3/wave), K=512 ----
        const int m0 = (blockIdx.x - 256) * 16;
        const float* aPtr = embeds + (size_t)(m0 + l15) * E_DIM + quad * 8;
        const int tb = wv * 3;
        const unsigned short* dSrc = wp + WP_V +
            ((size_t)tb * 16 + (lane >> 2)) * 512 + (lane & 3) * 8;

        f32x4 acc[3];
#pragma unroll
        for (int t = 0; t < 3; ++t)
#pragma unroll
            for (int i = 0; i < 4; ++i) acc[t][i] = 0.f;
        float4 aReg[3][2];

#define EB_LOADA(slot, c) { aReg[slot][0] = ld4(aPtr + (c) * 32); \
                            aReg[slot][1] = ld4(aPtr + (c) * 32 + 4); }
#define EB_DMA(c) { _Pragma("unroll")                                      \
        for (int t = 0; t < 3; ++t)                                        \
            dma16(dSrc + (size_t)t * 8192 + (c) * 32,                      \
                  &Bst[(c) & 1][wv][t][0]); }
#define EB_BODY(c, WN, DOD, DOA) {                                         \
        bf16x8 af = cvt_regs(aReg[(c) % 3]);                               \
        waitv<WN>();                                                       \
        const unsigned short* Bw = &Bst[(c) & 1][wv][0][0];                \
        _Pragma("unroll")                                                  \
        for (int t = 0; t < 3; ++t) {                                      \
            bf16x8 bf = *(const bf16x8*)(Bw + t * 512 + l15 * 32 + quad * 8); \
            acc[t] = __builtin_amdgcn_mfma_f32_16x16x32_bf16(af, bf, acc[t], 0, 0, 0); \
        }                                                                  \
        CFENCE;                                                            \
        if (DOD) EB_DMA((c) + 2);                                          \
        CFENCE;                                                            \
        if (DOA) EB_LOADA((c) % 3, (c) + 3);                               \
        CFENCE; }

        EB_LOADA(0, 0); CFENCE;
        EB_DMA(0); CFENCE;
        EB_LOADA(1, 1); CFENCE;
        EB_DMA(1); CFENCE;
        EB_LOADA(2, 2); CFENCE;

        for (int c = 0; c <= 13; ++c) EB_BODY(c, 7, true, (c + 3) < 16);
        EB_BODY(14, 5, false, false);
        EB_BODY(15, 0, false, false);

        unsigned short* P3 = Pb + PB_P3;
#pragma unroll
        for (int t = 0; t < 3; ++t) {
            const int tg = tb + t;
            if (tg < 10) {
                const int col = tg * 16 + l15;
#pragma unroll
                for (int i = 0; i < 4; ++i)
                    P3[(size_t)(m0 + quad * 4 + i) * PR + col] =
                        (col < HID) ? f2bf(acc[t][i]) : (unsigned short)0;
            }
        }
    }
}

// ---------------------------------------------------------------------------
// Span kernel: 32 spans/block, grid 1024. Gather-combine from bf16 P
// (XCD-L2 resident) -> h1 bf16 in LDS; layer2 MFMA; layer3 shuffle-reduce.
// ---------------------------------------------------------------------------
__global__ __launch_bounds__(256) void span_kernel(
    const unsigned short* __restrict__ Pb, const float* __restrict__ attns,
    const unsigned short* __restrict__ wp,
    const int* __restrict__ span_starts, const int* __restrict__ span_widths,
    const float* __restrict__ bs1, const float* __restrict__ bs2,
    const float* __restrict__ Ws3, const float* __restrict__ bs3,
    float* __restrict__ out)
{
    __shared__ unsigned short sHb[32][168];
    __shared__ float s_wgt[32][W_MAX];
    __shared__ int s_st[32], s_wd[32], s_bin[32];
    __shared__ float sPart[4][32];
    __shared__ float sb1[KP2];

    const int tid = threadIdx.x;
    const int n0s = blockIdx.x * 32;

    if (tid < KP2) sb1[tid] = (tid < HID) ? bs1[tid] : 0.f;
    if (tid < 32) {
        int st = span_starts[n0s + tid], wd = span_widths[n0s + tid];
        s_st[tid] = st; s_wd[tid] = wd;
        s_bin[tid] = (wd >= 1) + (wd >= 2) + (wd >= 3) + (wd >= 4) +
                     (wd >= 8) + (wd >= 16) + (wd >= 32) + (wd >= 64);
        float lg[W_MAX];
        float m = -1e30f;
#pragma unroll
        for (int w = 0; w < W_MAX; ++w)
            if (w < wd) { float a = attns[st + w]; lg[w] = a; m = fmaxf(m, a); }
        float sum = 0.f;
#pragma unroll
        for (int w = 0; w < W_MAX; ++w) {
            float e = (w < wd) ? __expf(lg[w] - m) : 0.f;
            lg[w] = e; sum += e;
        }
        float inv = 1.f / sum;
#pragma unroll
        for (int w = 0; w < W_MAX; ++w) s_wgt[tid][w] = lg[w] * inv;
    }
    __syncthreads();

    // gather-combine: 8 lanes/span, bf16x8 chunks
    {
        const unsigned short* P1b = Pb + PB_P1;
        const unsigned short* P2b = Pb + PB_P2;
        const unsigned short* P3b = Pb + PB_P3;
        const unsigned short* WEb = wp + WP_WE1;
        const int s = tid >> 3, jl = tid & 7;
        const int st = s_st[s], wd = s_wd[s];
        const size_t rs = (size_t)st * PR;
        const size_t re = (size_t)(st + wd - 1) * PR;
        const size_t rb = (size_t)s_bin[s] * PR;
        for (int c = jl; c < 20; c += 8) {
            const int j = c * 8;
            bf16x8 u1 = *(const bf16x8*)(P1b + rs + j);
            bf16x8 u2 = *(const bf16x8*)(P2b + re + j);
            bf16x8 uw = *(const bf16x8*)(WEb + rb + j);
            float acc[8];
#pragma unroll
            for (int i = 0; i < 8; ++i)
                acc[i] = bf2f(u1[i]) + bf2f(u2[i]) + bf2f(uw[i]) + sb1[j + i];
#pragma unroll
            for (int w = 0; w < W_MAX; ++w) {
                if (w < wd) {
                    float wt = s_wgt[s][w];
                    bf16x8 uv = *(const bf16x8*)(P3b + rs + (size_t)w * PR + j);
#pragma unroll
                    for (int i = 0; i < 8; ++i)
                        acc[i] = fmaf(wt, bf2f(uv[i]), acc[i]);
                }
            }
            bf16x8 pk;
#pragma unroll
            for (int i = 0; i < 8; ++i) pk[i] = (short)f2bf(fmaxf(acc[i], 0.f));
            *(bf16x8*)&sHb[s][j] = pk;
        }
    }
    __syncthreads();

    // layer2 MFMA: M=32 (2 m-tiles), N=160 (tiles 3,3,2,2 over waves)
    const int wv = tid >> 6, lane = tid & 63, l15 = lane & 15, quad = lane >> 4;
    const int nb = (wv < 2) ? wv * 3 : 6 + (wv - 2) * 2;
    const int cnt = (wv < 2) ? 3 : 2;

    f32x4 a2[2][3];
#pragma unroll
    for (int mt = 0; mt < 2; ++mt)
#pragma unroll
        for (int t = 0; t < 3; ++t)
#pragma unroll
            for (int i = 0; i < 4; ++i) a2[mt][t][i] = 0.f;

#pragma unroll
    for (int c = 0; c < 5; ++c) {
        int k0 = c * 32;
        bf16x8 af0 = *(const bf16x8*)&sHb[l15][k0 + quad * 8];
        bf16x8 af1 = *(const bf16x8*)&sHb[16 + l15][k0 + quad * 8];
#pragma unroll
        for (int t = 0; t < 3; ++t) {
            if (t < cnt) {
                bf16x8 b = *(const bf16x8*)(wp + WP_S2 +
                            (size_t)((nb + t) * 16 + l15) * KP2 + k0 + quad * 8);
                a2[0][t] = __builtin_amdgcn_mfma_f32_16x16x32_bf16(af0, b, a2[0][t], 0, 0, 0);
                a2[1][t] = __builtin_amdgcn_mfma_f32_16x16x32_bf16(af1, b, a2[1][t], 0, 0, 0);
            }
        }
    }

    float sc[2][4];
#pragma unroll
    for (int mt = 0; mt < 2; ++mt)
#pragma unroll
        for (int i = 0; i < 4; ++i) sc[mt][i] = 0.f;
#pragma unroll
    for (int t = 0; t < 3; ++t) {
        if (t < cnt) {
            int col = (nb + t) * 16 + l15;
            float w3 = (col < HID) ? Ws3[col] : 0.f;
            float b2 = (col < HID) ? bs2[col] : 0.f;
#pragma unroll
            for (int mt = 0; mt < 2; ++mt)
#pragma unroll
                for (int i = 0; i < 4; ++i)
                    sc[mt][i] = fmaf(fmaxf(a2[mt][t][i] + b2, 0.f), w3, sc[mt][i]);
        }
    }
#pragma unroll
    for (int off = 8; off >= 1; off >>= 1)
#pragma unroll
        for (int mt = 0; mt < 2; ++mt)
#pragma unroll
            for (int i = 0; i < 4; ++i)
                sc[mt][i] += __shfl_down(sc[mt][i], off, 16);
    if (l15 == 0) {
#pragma unroll
        for (int mt = 0; mt < 2; ++mt)
#pragma unroll
            for (int i = 0; i < 4; ++i)
                sPart[wv][mt * 16 + quad * 4 + i] = sc[mt][i];
    }
    __syncthreads();
    if (tid < 32)
        out[n0s + tid] = sPart[0][tid] + sPart[1][tid] + sPart[2][tid] +
                         sPart[3][tid] + bs3[0];
}

// ---------------------------------------------------------------------------
extern "C" void kernel_launch(void* const* d_in, const int* in_sizes, int n_in,
                              void* d_out, int out_size, void* d_ws, size_t ws_size,
                              hipStream_t stream)
{
    const float* states      = (const float*)d_in[0];
    const float* embeds      = (const float*)d_in[1];
    const int*   span_starts = (const int*)d_in[2];
    const int*   span_widths = (const int*)d_in[3];
    const float* Wa1 = (const float*)d_in[4];
    const float* ba1 = (const float*)d_in[5];
    const float* Wa2 = (const float*)d_in[6];
    const float* ba2 = (const float*)d_in[7];
    const float* Wa3 = (const float*)d_in[8];
    const float* ba3 = (const float*)d_in[9];
    const float* width_emb = (const float*)d_in[10];
    const float* Ws1 = (const float*)d_in[11];
    const float* bs1 = (const float*)d_in[12];
    const float* Ws2 = (const float*)d_in[13];
    const float* bs2 = (const float*)d_in[14];
    const float* Ws3 = (const float*)d_in[15];
    const float* bs3 = (const float*)d_in[16];
    float* out = (float*)d_out;

    float* ws    = (float*)d_ws;
    float* attns = ws + WS_ATTNS;
    unsigned short* Pb    = (unsigned short*)(ws + WS_PB);
    unsigned short* wpack = (unsigned short*)(ws + WS_WPACK);

    hipLaunchKernelGGL(prepack_kernel, dim3((PK_QUADS + 255) / 256), dim3(256), 0, stream,
                       Wa1, Ws1, Wa2, Ws2, width_emb, wpack);
    hipLaunchKernelGGL(token_kernel, dim3(512), dim3(256), 0, stream,
                       states, embeds, wpack, ba1, ba2, Wa3, ba3, Pb, attns);
    hipLaunchKernelGGL(span_kernel, dim3(N_SPAN / 32), dim3(256), 0, stream,
                       Pb, attns, wpack, span_starts, span_widths,
                       bs1, bs2, Ws3, bs3, out);
}

// Round 9
// 171.246 us; speedup vs baseline: 1.2314x; 1.0148x over previous
//
#include <hip/hip_runtime.h>
#include <math.h>

#define T_TOK 4096
#define A_DIM 1024
#define E_DIM 512
#define N_SPAN 32768
#define W_MAX 10
#define HID 150
#define FD 20

#define PR  160             // P row stride (bf16 elems); cols 150..159 zero
#define KP2 160             // padded K/N for the 150x150 layers

// ---- workspace layout (float offsets) ----
// attns: [0, 4096)
// Pb:    [4096, 987136)        = 1,966,080 ushorts (3 x 4096 x 160)
// wpack: [987136, 1300176)     = 626,080 ushorts
#define WS_ATTNS 0
#define WS_PB    4096
#define WS_WPACK 987136
// Pb ushort offsets
#define PB_P1 0
#define PB_P2 655360
#define PB_P3 1310720
// wpack ushort offsets
#define WP_ST  0             // 3 cb x 32 c x [160 n x 4 qsw x 8]  (chunk-contig, swizzled)
#define WP_V   491520        // 16 c x [160 n x 4 qsw x 8]
#define WP_A2  573440        // [160][160] n-major
#define WP_S2  599040        // [160][160] n-major
#define WP_WE1 624640        // [9][160]
#define WP_TOTAL 626080

typedef short  bf16x8 __attribute__((ext_vector_type(8)));
typedef float  f32x4  __attribute__((ext_vector_type(4)));

__device__ __forceinline__ float4 ld4(const float* p) { return *(const float4*)p; }

__device__ __forceinline__ unsigned short f2bf(float f) {
    unsigned u = __float_as_uint(f);
    unsigned r = u + 0x7fffu + ((u >> 16) & 1u);   // RNE
    return (unsigned short)(r >> 16);
}
__device__ __forceinline__ float bf2f(short s) {
    return __uint_as_float(((unsigned)(unsigned short)s) << 16);
}
__device__ __forceinline__ bf16x8 cvt_regs(const float4* a) {
    bf16x8 f;
    f[0] = (short)f2bf(a[0].x); f[1] = (short)f2bf(a[0].y);
    f[2] = (short)f2bf(a[0].z); f[3] = (short)f2bf(a[0].w);
    f[4] = (short)f2bf(a[1].x); f[5] = (short)f2bf(a[1].y);
    f[6] = (short)f2bf(a[1].z); f[7] = (short)f2bf(a[1].w);
    return f;
}

// async global->LDS, 16 B per lane; LDS dst is wave-uniform base + lane*16
typedef const __attribute__((address_space(1))) unsigned int as1_u32;
typedef __attribute__((address_space(3))) unsigned int as3_u32;
__device__ __forceinline__ void dma16(const void* g, void* l) {
    __builtin_amdgcn_global_load_lds((as1_u32*)g, (as3_u32*)l, 16, 0, 0);
}
__device__ __forceinline__ void waitv0() {
    asm volatile("s_waitcnt vmcnt(0)" ::: "memory");
}

// ---------------------------------------------------------------------------
// Prepack: weights -> bf16 chunk-contiguous swizzled layout for DMA staging
// (piece (n,q) of chunk c stored at qsw = q ^ ((n>>1)&3) so ds_read_b128
// covers all 8 bank-granules, 2-way only), plus Wa2/Ws2 n-major and WE1.
// ---------------------------------------------------------------------------
__global__ __launch_bounds__(256) void prepack_kernel(
    const float* __restrict__ Wa1, const float* __restrict__ Ws1,
    const float* __restrict__ Wa2, const float* __restrict__ Ws2,
    const float* __restrict__ width_emb, unsigned short* __restrict__ wp)
{
    int idx = blockIdx.x * 256 + threadIdx.x;
    if (idx < 122880) {
        // ST: (cb, c, koff, ngrp)
        int cb = idx / 40960, r = idx % 40960;
        int c = r / 1280, r2 = r % 1280;
        int koff = r2 / 40, ngrp = r2 % 40;
        int k = c * 32 + koff;
        const float* W = (cb == 0) ? Wa1 : Ws1 + (size_t)(cb - 1) * 1024 * HID;
        int q = koff >> 3, off = koff & 7;
        unsigned short* dst = wp + WP_ST + cb * 163840 + c * 5120;
#pragma unroll
        for (int i = 0; i < 4; ++i) {
            int n = ngrp * 4 + i;
            float v = (n < HID) ? W[(size_t)k * HID + n] : 0.f;
            int qsw = q ^ ((n >> 1) & 3);
            dst[n * 32 + qsw * 8 + off] = f2bf(v);
        }
    } else if (idx < 143360) {
        // V: (c, koff, ngrp), K=512
        int r = idx - 122880;
        int c = r / 1280, r2 = r % 1280;
        int koff = r2 / 40, ngrp = r2 % 40;
        int k = c * 32 + koff;
        int q = koff >> 3, off = koff & 7;
        unsigned short* dst = wp + WP_V + c * 5120;
#pragma unroll
        for (int i = 0; i < 4; ++i) {
            int n = ngrp * 4 + i;
            float v = (n < HID) ? Ws1[(size_t)(2048 + k) * HID + n] : 0.f;
            int qsw = q ^ ((n >> 1) & 3);
            dst[n * 32 + qsw * 8 + off] = f2bf(v);
        }
    } else if (idx < 149760) {
        int r = idx - 143360;
        int n = r / 40, k0 = (r % 40) * 4;
#pragma unroll
        for (int j = 0; j < 4; ++j) {
            int k = k0 + j;
            float v = (n < HID && k < HID) ? Wa2[(size_t)k * HID + n] : 0.f;
            wp[WP_A2 + n * KP2 + k] = f2bf(v);
        }
    } else if (idx < 156160) {
        int r = idx - 149760;
        int n = r / 40, k0 = (r % 40) * 4;
#pragma unroll
        for (int j = 0; j < 4; ++j) {
            int k = k0 + j;
            float v = (n < HID && k < HID) ? Ws2[(size_t)k * HID + n] : 0.f;
            wp[WP_S2 + n * KP2 + k] = f2bf(v);
        }
    } else if (idx < 156520) {
        int r = idx - 156160;
        int b = r / 40, n0 = (r % 40) * 4;
#pragma unroll
        for (int j = 0; j < 4; ++j) {
            int n = n0 + j;
            float a = 0.f;
            if (n < HID)
                for (int kk = 0; kk < FD; ++kk)
                    a = fmaf(width_emb[b * FD + kk], Ws1[(size_t)(2560 + kk) * HID + n], a);
            wp[WP_WE1 + b * KP2 + n] = f2bf(a);
        }
    }
}

// ---------------------------------------------------------------------------
// Token kernel: 256 blocks x 4 waves, shared-LDS B double-buffer (DMA,
// swizzled), A in registers with 1-chunk-ahead fp32 prefetch + cvt.
//   bid 0..63   : states x Wa1   (cb0) -> fused attn tail -> attns
//   bid 64..191 : states x Ws1a/b (cb1/2) -> P1/P2 bf16
//   bid 192..255: embeds x V (NC=16)      -> P3 bf16
// ---------------------------------------------------------------------------
__global__ __launch_bounds__(256) void token_kernel(
    const float* __restrict__ states, const float* __restrict__ embeds,
    const unsigned short* __restrict__ wp,
    const float* __restrict__ ba1, const float* __restrict__ ba2,
    const float* __restrict__ Wa3, const float* __restrict__ ba3,
    unsigned short* __restrict__ Pb, float* __restrict__ attns)
{
    __shared__ __align__(16) unsigned short buf[2][5376];   // 21.5 KB total

    const int tid = threadIdx.x;
    const int wv = tid >> 6, lane = tid & 63, l15 = lane & 15, quad = lane >> 4;
    const int bid = blockIdx.x;
    const int isEmb = (bid >= 192) ? 1 : 0;
    const int cb = isEmb ? 3 : (bid >> 6);
    const int mb = bid & 63;
    const int NC = isEmb ? 16 : 32;
    const unsigned short* srcB = isEmb ? (wp + WP_V) : (wp + WP_ST + cb * 163840);
    const float* srcA = isEmb
        ? (embeds + (size_t)(mb * 64 + wv * 16 + l15) * E_DIM + quad * 8)
        : (states + (size_t)(mb * 64 + wv * 16 + l15) * A_DIM + quad * 8);
    const int swz8 = (quad ^ ((l15 >> 1) & 3)) * 8;
    const int bl = l15 * 32 + swz8;

    f32x4 acc[10];
#pragma unroll
    for (int t = 0; t < 10; ++t)
#pragma unroll
        for (int i = 0; i < 4; ++i) acc[t][i] = 0.f;

    float4 aR[2][2];

#define DMAB(c) do {                                                        \
        unsigned short* lB = &buf[(c) & 1][0];                              \
        const unsigned short* gB = srcB + (size_t)(c) * 5120;               \
        dma16(gB + (wv * 64 + lane) * 8,       lB + wv * 512);              \
        dma16(gB + (256 + wv * 64 + lane) * 8, lB + 2048 + wv * 512);       \
        if (wv < 2)                                                         \
            dma16(gB + (512 + wv * 64 + lane) * 8, lB + 4096 + wv * 512);   \
    } while (0)
#define LDA(c) do {                                                         \
        aR[(c) & 1][0] = ld4(srcA + (c) * 32);                              \
        aR[(c) & 1][1] = ld4(srcA + (c) * 32 + 4);                          \
    } while (0)

    LDA(0);
    DMAB(0);
    for (int c = 0; c < NC; ++c) {
        waitv0();                 // B(c) in LDS + A(c) regs ready (all waves'
        __syncthreads();          // own DMAs done before anyone proceeds)
        if (c + 1 < NC) { DMAB(c + 1); LDA(c + 1); }
        bf16x8 af = cvt_regs(aR[c & 1]);
        const unsigned short* bb = &buf[c & 1][0];
#pragma unroll
        for (int t = 0; t < 10; ++t) {
            bf16x8 bf = *(const bf16x8*)(bb + t * 512 + bl);
            acc[t] = __builtin_amdgcn_mfma_f32_16x16x32_bf16(af, bf, acc[t], 0, 0, 0);
        }
    }
    __syncthreads();   // all reads of buf done before aliasing below

    const int m0 = mb * 64;
    if (cb >= 1) {
        unsigned short* Pg = Pb + (size_t)(cb - 1) * 655360;  // cb1->P1, cb2->P2, emb->P3
        const int rowb = m0 + wv * 16 + quad * 4;
#pragma unroll
        for (int t = 0; t < 10; ++t) {
            const int col = t * 16 + l15;
#pragma unroll
            for (int i = 0; i < 4; ++i)
                Pg[(size_t)(rowb + i) * PR + col] =
                    (col < HID) ? f2bf(acc[t][i]) : (unsigned short)0;
        }
    } else {
        // fused attn tail: h1a (64x168 = 10752 ushorts) aliases buf exactly
        unsigned short (*h1a)[168] = (unsigned short (*)[168]) & buf[0][0];
#pragma unroll
        for (int t = 0; t < 10; ++t) {
            const int col = t * 16 + l15;
            const float bv = (col < HID) ? ba1[col] : 0.f;
#pragma unroll
            for (int i = 0; i < 4; ++i)
                h1a[wv * 16 + quad * 4 + i][col] = f2bf(fmaxf(acc[t][i] + bv, 0.f));
        }
        __syncthreads();

        f32x4 a2[10];
#pragma unroll
        for (int t = 0; t < 10; ++t)
#pragma unroll
            for (int i = 0; i < 4; ++i) a2[t][i] = 0.f;
#pragma unroll
        for (int kc = 0; kc < 5; ++kc) {
            const int k0 = kc * 32;
            bf16x8 af2 = *(const bf16x8*)&h1a[wv * 16 + l15][k0 + quad * 8];
#pragma unroll
            for (int t = 0; t < 10; ++t) {
                bf16x8 b = *(const bf16x8*)(wp + WP_A2 +
                            (size_t)(t * 16 + l15) * KP2 + k0 + quad * 8);
                a2[t] = __builtin_amdgcn_mfma_f32_16x16x32_bf16(af2, b, a2[t], 0, 0, 0);
            }
        }
        float sc[4] = {0.f, 0.f, 0.f, 0.f};
#pragma unroll
        for (int t = 0; t < 10; ++t) {
            const int col = t * 16 + l15;
            const float w3 = (col < HID) ? Wa3[col] : 0.f;
            const float b2 = (col < HID) ? ba2[col] : 0.f;
#pragma unroll
            for (int i = 0; i < 4; ++i)
                sc[i] = fmaf(fmaxf(a2[t][i] + b2, 0.f), w3, sc[i]);
        }
#pragma unroll
        for (int off = 8; off >= 1; off >>= 1)
#pragma unroll
            for (int i = 0; i < 4; ++i) sc[i] += __shfl_down(sc[i], off, 16);
        if (l15 == 0) {
            const float b3 = ba3[0];
#pragma unroll
            for (int i = 0; i < 4; ++i)
                attns[m0 + wv * 16 + quad * 4 + i] = sc[i] + b3;
        }
    }
#undef DMAB
#undef LDA
}

// ---------------------------------------------------------------------------
// Span kernel: 32 spans/block, grid 1024. Gather-combine from bf16 P
// (XCD-L2 resident) -> h1 bf16 in LDS; layer2 MFMA; layer3 shuffle-reduce.
// ---------------------------------------------------------------------------
__global__ __launch_bounds__(256) void span_kernel(
    const unsigned short* __restrict__ Pb, const float* __restrict__ attns,
    const unsigned short* __restrict__ wp,
    const int* __restrict__ span_starts, const int* __restrict__ span_widths,
    const float* __restrict__ bs1, const float* __restrict__ bs2,
    const float* __restrict__ Ws3, const float* __restrict__ bs3,
    float* __restrict__ out)
{
    __shared__ unsigned short sHb[32][168];
    __shared__ float s_wgt[32][W_MAX];
    __shared__ int s_st[32], s_wd[32], s_bin[32];
    __shared__ float sPart[4][32];
    __shared__ float sb1[KP2];

    const int tid = threadIdx.x;
    const int n0s = blockIdx.x * 32;

    if (tid < KP2) sb1[tid] = (tid < HID) ? bs1[tid] : 0.f;
    if (tid < 32) {
        int st = span_starts[n0s + tid], wd = span_widths[n0s + tid];
        s_st[tid] = st; s_wd[tid] = wd;
        s_bin[tid] = (wd >= 1) + (wd >= 2) + (wd >= 3) + (wd >= 4) +
                     (wd >= 8) + (wd >= 16) + (wd >= 32) + (wd >= 64);
        float lg[W_MAX];
        float m = -1e30f;
#pragma unroll
        for (int w = 0; w < W_MAX; ++w)
            if (w < wd) { float a = attns[st + w]; lg[w] = a; m = fmaxf(m, a); }
        float sum = 0.f;
#pragma unroll
        for (int w = 0; w < W_MAX; ++w) {
            float e = (w < wd) ? __expf(lg[w] - m) : 0.f;
            lg[w] = e; sum += e;
        }
        float inv = 1.f / sum;
#pragma unroll
        for (int w = 0; w < W_MAX; ++w) s_wgt[tid][w] = lg[w] * inv;
    }
    __syncthreads();

    // gather-combine: 8 lanes/span, bf16x8 chunks
    {
        const unsigned short* P1b = Pb + PB_P1;
        const unsigned short* P2b = Pb + PB_P2;
        const unsigned short* P3b = Pb + PB_P3;
        const unsigned short* WEb = wp + WP_WE1;
        const int s = tid >> 3, jl = tid & 7;
        const int st = s_st[s], wd = s_wd[s];
        const size_t rs = (size_t)st * PR;
        const size_t re = (size_t)(st + wd - 1) * PR;
        const size_t rb = (size_t)s_bin[s] * PR;
        for (int c = jl; c < 20; c += 8) {
            const int j = c * 8;
            bf16x8 u1 = *(const bf16x8*)(P1b + rs + j);
            bf16x8 u2 = *(const bf16x8*)(P2b + re + j);
            bf16x8 uw = *(const bf16x8*)(WEb + rb + j);
            float acc[8];
#pragma unroll
            for (int i = 0; i < 8; ++i)
                acc[i] = bf2f(u1[i]) + bf2f(u2[i]) + bf2f(uw[i]) + sb1[j + i];
#pragma unroll
            for (int w = 0; w < W_MAX; ++w) {
                if (w < wd) {
                    float wt = s_wgt[s][w];
                    bf16x8 uv = *(const bf16x8*)(P3b + rs + (size_t)w * PR + j);
#pragma unroll
                    for (int i = 0; i < 8; ++i)
                        acc[i] = fmaf(wt, bf2f(uv[i]), acc[i]);
                }
            }
            bf16x8 pk;
#pragma unroll
            for (int i = 0; i < 8; ++i) pk[i] = (short)f2bf(fmaxf(acc[i], 0.f));
            *(bf16x8*)&sHb[s][j] = pk;
        }
    }
    __syncthreads();

    // layer2 MFMA: M=32 (2 m-tiles), N=160 (tiles 3,3,2,2 over waves)
    const int wv = tid >> 6, lane = tid & 63, l15 = lane & 15, quad = lane >> 4;
    const int nb = (wv < 2) ? wv * 3 : 6 + (wv - 2) * 2;
    const int cnt = (wv < 2) ? 3 : 2;

    f32x4 a2[2][3];
#pragma unroll
    for (int mt = 0; mt < 2; ++mt)
#pragma unroll
        for (int t = 0; t < 3; ++t)
#pragma unroll
            for (int i = 0; i < 4; ++i) a2[mt][t][i] = 0.f;

#pragma unroll
    for (int c = 0; c < 5; ++c) {
        int k0 = c * 32;
        bf16x8 af0 = *(const bf16x8*)&sHb[l15][k0 + quad * 8];
        bf16x8 af1 = *(const bf16x8*)&sHb[16 + l15][k0 + quad * 8];
#pragma unroll
        for (int t = 0; t < 3; ++t) {
            if (t < cnt) {
                bf16x8 b = *(const bf16x8*)(wp + WP_S2 +
                            (size_t)((nb + t) * 16 + l15) * KP2 + k0 + quad * 8);
                a2[0][t] = __builtin_amdgcn_mfma_f32_16x16x32_bf16(af0, b, a2[0][t], 0, 0, 0);
                a2[1][t] = __builtin_amdgcn_mfma_f32_16x16x32_bf16(af1, b, a2[1][t], 0, 0, 0);
            }
        }
    }

    float sc[2][4];
#pragma unroll
    for (int mt = 0; mt < 2; ++mt)
#pragma unroll
        for (int i = 0; i < 4; ++i) sc[mt][i] = 0.f;
#pragma unroll
    for (int t = 0; t < 3; ++t) {
        if (t < cnt) {
            int col = (nb + t) * 16 + l15;
            float w3 = (col < HID) ? Ws3[col] : 0.f;
            float b2 = (col < HID) ? bs2[col] : 0.f;
#pragma unroll
            for (int mt = 0; mt < 2; ++mt)
#pragma unroll
                for (int i = 0; i < 4; ++i)
                    sc[mt][i] = fmaf(fmaxf(a2[mt][t][i] + b2, 0.f), w3, sc[mt][i]);
        }
    }
#pragma unroll
    for (int off = 8; off >= 1; off >>= 1)
#pragma unroll
        for (int mt = 0; mt < 2; ++mt)
#pragma unroll
            for (int i = 0; i < 4; ++i)
                sc[mt][i] += __shfl_down(sc[mt][i], off, 16);
    if (l15 == 0) {
#pragma unroll
        for (int mt = 0; mt < 2; ++mt)
#pragma unroll
            for (int i = 0; i < 4; ++i)
                sPart[wv][mt * 16 + quad * 4 + i] = sc[mt][i];
    }
    __syncthreads();
    if (tid < 32)
        out[n0s + tid] = sPart[0][tid] + sPart[1][tid] + sPart[2][tid] +
                         sPart[3][tid] + bs3[0];
}

// ---------------------------------------------------------------------------
extern "C" void kernel_launch(void* const* d_in, const int* in_sizes, int n_in,
                              void* d_out, int out_size, void* d_ws, size_t ws_size,
                              hipStream_t stream)
{
    const float* states      = (const float*)d_in[0];
    const float* embeds      = (const float*)d_in[1];
    const int*   span_starts = (const int*)d_in[2];
    const int*   span_widths = (const int*)d_in[3];
    const float* Wa1 = (const float*)d_in[4];
    const float* ba1 = (const float*)d_in[5];
    const float* Wa2 = (const float*)d_in[6];
    const float* ba2 = (const float*)d_in[7];
    const float* Wa3 = (const float*)d_in[8];
    const float* ba3 = (const float*)d_in[9];
    const float* width_emb = (const float*)d_in[10];
    const float* Ws1 = (const float*)d_in[11];
    const float* bs1 = (const float*)d_in[12];
    const float* Ws2 = (const float*)d_in[13];
    const float* bs2 = (const float*)d_in[14];
    const float* Ws3 = (const float*)d_in[15];
    const float* bs3 = (const float*)d_in[16];
    float* out = (float*)d_out;

    float* ws    = (float*)d_ws;
    float* attns = ws + WS_ATTNS;
    unsigned short* Pb    = (unsigned short*)(ws + WS_PB);
    unsigned short* wpack = (unsigned short*)(ws + WS_WPACK);

    hipLaunchKernelGGL(prepack_kernel, dim3(612), dim3(256), 0, stream,
                       Wa1, Ws1, Wa2, Ws2, width_emb, wpack);
    hipLaunchKernelGGL(token_kernel, dim3(256), dim3(256), 0, stream,
                       states, embeds, wpack, ba1, ba2, Wa3, ba3, Pb, attns);
    hipLaunchKernelGGL(span_kernel, dim3(N_SPAN / 32), dim3(256), 0, stream,
                       Pb, attns, wpack, span_starts, span_widths,
                       bs1, bs2, Ws3, bs3, out);
}